// Round 1
// baseline (270002.441 us; speedup 1.0000x reference)
//
#include <hip/hip_runtime.h>
#include <cstdint>
#include <cstddef>

#define SEQ       32768
#define NT        512
#define START_TAG 510
#define END_TAG   511
#define NEGF      -10000.0f
#define KCH       64
#define NCH       (SEQ / KCH)   /* 512 chunks */

/* workspace layout (all 16B aligned) */
#define BP_BYTES  ((size_t)SEQ * NT * sizeof(unsigned short))   /* 32 MiB  backpointers */
#define M_BYTES   ((size_t)NCH * NT * sizeof(unsigned short))   /* 512 KiB chunk-composed maps */
#define BD_BYTES  ((size_t)NCH * sizeof(int))                   /* 2 KiB   chunk boundary tags */
#define TRT_OFF   (BP_BYTES + M_BYTES + BD_BYTES)
#define WS_NEEDED (TRT_OFF + (size_t)NT * NT * sizeof(float))

/* ---------- kernel 1: transpose trans (512x512) so forward loop is coalesced ---------- */
__global__ __launch_bounds__(1024) void transpose_k(const float* __restrict__ tr,
                                                    float* __restrict__ trT) {
    __shared__ float tile[32][33];
    const int bx = blockIdx.x * 32, by = blockIdx.y * 32;
    const int tx = threadIdx.x, ty = threadIdx.y;
    tile[ty][tx] = tr[(size_t)(by + ty) * NT + (bx + tx)];
    __syncthreads();
    trT[(size_t)(bx + ty) * NT + (by + tx)] = tile[tx][ty];
}

/* ---------- kernel 2: single-workgroup sequential Viterbi forward pass ---------- */
__global__ __launch_bounds__(1024) void viterbi_fwd(const float* __restrict__ u,
                                                    const float* __restrict__ tr,
                                                    const float* __restrict__ trT,
                                                    unsigned short* __restrict__ bp,
                                                    unsigned short* __restrict__ M,
                                                    int* __restrict__ boundary,
                                                    float* __restrict__ out) {
    __shared__ float alphas[2][NT];
    __shared__ float pval[8][NT];
    __shared__ int   pidx[8][NT];
    __shared__ unsigned short Rbuf[2][NT];   /* composed backptr map, ping-pong */
    __shared__ float wv[16];
    __shared__ int   wi[16];

    const int tid   = threadIdx.x;
    const int ic    = tid >> 7;      /* i-chunk 0..7 (64 i's each)   */
    const int jt    = tid & 127;     /* j-quad index                 */
    const int j4    = jt << 2;       /* first of 4 output tags owned */
    const int ibase = ic << 6;

    if (tid < NT) alphas[0][tid] = (tid == START_TAG) ? 0.0f : NEGF;
    __syncthreads();

    int cur = 0;
    float ureg = 0.0f, unext = 0.0f;
    if (tid < NT) ureg = u[tid];     /* u[t=0] prefetched */

    for (int t = 0; t < SEQ; ++t) {
        /* prefetch next step's unary row; latency hidden under the dense scan */
        if (tid < NT && (t + 1) < SEQ) unext = u[(size_t)(t + 1) * NT + tid];

        const float* ac = alphas[cur];
        /* dense max-plus: this thread covers i in [ibase,ibase+64) for 4 j's.
           Ties: strict '>' + ascending i scan => lowest index wins (jnp.argmax). */
        float bv0 = -INFINITY, bv1 = -INFINITY, bv2 = -INFINITY, bv3 = -INFINITY;
        int   bi0 = 0, bi1 = 0, bi2 = 0, bi3 = 0;
        const float* trow = trT + (size_t)ibase * NT + j4;
        #pragma unroll 4
        for (int k = 0; k < 64; ++k) {
            const int   i   = ibase + k;
            const float a   = ac[i];
            const float4 t4 = *reinterpret_cast<const float4*>(trow + (size_t)k * NT);
            float s;
            s = a + t4.x; if (s > bv0) { bv0 = s; bi0 = i; }
            s = a + t4.y; if (s > bv1) { bv1 = s; bi1 = i; }
            s = a + t4.z; if (s > bv2) { bv2 = s; bi2 = i; }
            s = a + t4.w; if (s > bv3) { bv3 = s; bi3 = i; }
        }
        pval[ic][j4 + 0] = bv0; pidx[ic][j4 + 0] = bi0;
        pval[ic][j4 + 1] = bv1; pidx[ic][j4 + 1] = bi1;
        pval[ic][j4 + 2] = bv2; pidx[ic][j4 + 2] = bi2;
        pval[ic][j4 + 3] = bv3; pidx[ic][j4 + 3] = bi3;
        __syncthreads();

        if (tid < NT) {
            /* merge the 8 i-chunks in ascending order (tie -> lower i) */
            float bv = pval[0][tid]; int bi = pidx[0][tid];
            #pragma unroll
            for (int c = 1; c < 8; ++c) {
                const float v = pval[c][tid];
                if (v > bv) { bv = v; bi = pidx[c][tid]; }
            }
            bp[(size_t)t * NT + tid] = (unsigned short)bi;

            /* composed map update: R_t[j] = R_{t-1}[bp_t[j]], reset each chunk */
            unsigned short rn;
            if ((t & (KCH - 1)) == 0) rn = (unsigned short)bi;
            else                      rn = Rbuf[(t ^ 1) & 1][bi];
            Rbuf[t & 1][tid] = rn;
            if ((t & (KCH - 1)) == (KCH - 1))
                M[(size_t)(t / KCH) * NT + tid] = rn;

            alphas[cur ^ 1][tid] = bv + ureg;   /* fl(vit + u_t[j]) exactly as ref */
        }
        ureg = unext;
        cur ^= 1;
        __syncthreads();
    }

    /* terminal: alphas_T + tr[END_TAG,:], argmax with lowest-index tie-break */
    float tv = -INFINITY; int ti = 0x7fffffff;
    if (tid < NT) { tv = alphas[cur][tid] + tr[(size_t)END_TAG * NT + tid]; ti = tid; }
    for (int off = 32; off > 0; off >>= 1) {
        const float ov = __shfl_down(tv, off);
        const int   oi = __shfl_down(ti, off);
        if (ov > tv || (ov == tv && oi < ti)) { tv = ov; ti = oi; }
    }
    const int wid = tid >> 6;
    if ((tid & 63) == 0) { wv[wid] = tv; wi[wid] = ti; }
    __syncthreads();

    if (tid == 0) {
        float bvv = wv[0]; int bii = wi[0];
        for (int w = 1; w < 16; ++w)
            if (wv[w] > bvv || (wv[w] == bvv && wi[w] < bii)) { bvv = wv[w]; bii = wi[w]; }
        out[SEQ] = bvv;                 /* path_score */
        __threadfence();                /* make sure M[] global writes are visible */
        int tag = bii;                  /* path[32767] */
        boundary[NCH - 1] = tag;
        for (int c = NCH - 1; c >= 1; --c) {
            tag = (int)M[(size_t)c * NT + tag];   /* L2-hot chase, 511 hops */
            boundary[c - 1] = tag;
        }
    }
}

/* ---------- kernel 3: 512 independent per-chunk local tracebacks ---------- */
__global__ __launch_bounds__(64) void traceback_k(const unsigned short* __restrict__ bp,
                                                  const int* __restrict__ boundary,
                                                  float* __restrict__ out) {
    if (threadIdx.x != 0) return;
    const int c    = blockIdx.x;
    int       tag  = boundary[c];            /* = path[(c+1)K - 1] */
    const int tend = (c + 1) * KCH - 1;
    out[tend] = (float)tag;
    for (int t = tend - 1; t >= c * KCH; --t) {
        tag = (int)bp[(size_t)(t + 1) * NT + tag];
        out[t] = (float)tag;
    }
}

extern "C" void kernel_launch(void* const* d_in, const int* in_sizes, int n_in,
                              void* d_out, int out_size, void* d_ws, size_t ws_size,
                              hipStream_t stream) {
    const float* unary = (const float*)d_in[0];   /* (32768,1,512) f32 */
    const float* trans = (const float*)d_in[1];   /* (1,512,512)   f32 */
    /* d_in[2] = lengths (int64) — unused by the reference */
    float* out = (float*)d_out;                   /* [0..32767]=path, [32768]=score */
    char*  ws  = (char*)d_ws;

    unsigned short* bp       = (unsigned short*)ws;
    unsigned short* M        = (unsigned short*)(ws + BP_BYTES);
    int*            boundary = (int*)(ws + BP_BYTES + M_BYTES);
    float*          trT      = (float*)(ws + TRT_OFF);
    (void)in_sizes; (void)n_in; (void)out_size; (void)ws_size;

    transpose_k<<<dim3(16, 16), dim3(32, 32), 0, stream>>>(trans, trT);
    viterbi_fwd<<<1, 1024, 0, stream>>>(unary, trans, trT, bp, M, boundary, out);
    traceback_k<<<NCH, 64, 0, stream>>>(bp, boundary, out);
}